// Round 2
// baseline (2162.524 us; speedup 1.0000x reference)
//
#include <hip/hip_runtime.h>

#define NH 64
#define NRELS 9
#define NEDGE 300000
#define NGRAPH 64
#define TOTROWS 250000
#define TOTSEG 660000
#define TOTEDGE (NRELS * NEDGE)

__constant__ int c_NS[4]     = {100000, 20000, 50000, 80000};
__constant__ int c_SRC[9]    = {0,0,0,2,3,1,2,3,3};
__constant__ int c_DST[9]    = {1,2,3,3,3,0,0,0,2};
__constant__ int c_XOFF[5]   = {0,100000,120000,170000,250000};
__constant__ int c_ASOFF[10] = {0,100000,200000,300000,350000,430000,450000,500000,580000,660000};
__constant__ int c_ADOFF[10] = {0,20000,70000,150000,230000,310000,410000,510000,610000,660000};

struct EdgePtrs { const int* s[9]; const int* d[9]; };

// ---------------- setup: wv_s/wv_d = W @ a  (per l,r,side), bias presums ----------------
__global__ void k_setup(const float* Wsrc, const float* Wdst, const float* asrc,
                        const float* adst, const float* bias, float* wv, float* bsum) {
  int b = blockIdx.x, j = threadIdx.x;
  if (b < 36) {
    int r = b % 9, q = b / 9;
    int l = q >> 1, side = q & 1;
    const float* W = (side ? Wdst : Wsrc) + (l * 9 + r) * 64 * 64;
    const float* a = (side ? adst : asrc) + (l * 9 + r) * 64;
    float s = 0.f;
    for (int i = 0; i < 64; ++i) s += W[j * 64 + i] * a[i];
    wv[(side ? 1152 : 0) + (l * 9 + r) * 64 + j] = s;
  } else {
    for (int l = 0; l < 2; ++l)
      for (int t = 0; t < 4; ++t) {
        float s = 0.f;
        for (int r = 0; r < 9; ++r)
          if (c_DST[r] == t) s += bias[(l * 9 + r) * 64 + j];
        bsum[(l * 4 + t) * 64 + j] = s;
      }
  }
}

// ---------------- CSR build over 660k (relation,dst) segments ----------------
__global__ void k_count(EdgePtrs Eg, int* cnt) {
  int gid = blockIdx.x * blockDim.x + threadIdx.x;
  if (gid >= TOTEDGE) return;
  int r = gid / NEDGE, e = gid - r * NEDGE;
  int d = Eg.d[r][e];
  atomicAdd(&cnt[c_ADOFF[r] + d], 1);
}

__global__ void k_scan1(const int* cnt, int* bsum, int n) {
  __shared__ int sd[256];
  int b = blockIdx.x, t = threadIdx.x;
  int base = b * 1024 + t * 4;
  int s = 0;
#pragma unroll
  for (int k = 0; k < 4; ++k) { int i = base + k; if (i < n) s += cnt[i]; }
  sd[t] = s; __syncthreads();
  for (int o = 128; o; o >>= 1) { if (t < o) sd[t] += sd[t + o]; __syncthreads(); }
  if (t == 0) bsum[b] = sd[0];
}

__global__ void k_scan2(int* bsum, int nb, int* rowptr, int n, int total) {
  __shared__ int sd[1024];
  int t = threadIdx.x;
  int v = (t < nb) ? bsum[t] : 0;
  sd[t] = v; __syncthreads();
  for (int o = 1; o < 1024; o <<= 1) {
    int x = (t >= o) ? sd[t - o] : 0; __syncthreads();
    sd[t] += x; __syncthreads();
  }
  if (t < nb) bsum[t] = sd[t] - v;   // exclusive
  if (t == 0) rowptr[n] = total;
}

__global__ void k_scan3(const int* cnt, const int* bsum, int* rowptr, int n) {
  __shared__ int sd[256];
  int b = blockIdx.x, t = threadIdx.x;
  int base = b * 1024 + t * 4;
  int v[4]; int s = 0;
#pragma unroll
  for (int k = 0; k < 4; ++k) { int i = base + k; v[k] = (i < n) ? cnt[i] : 0; s += v[k]; }
  sd[t] = s; __syncthreads();
  int tot = s;
  for (int o = 1; o < 256; o <<= 1) {
    int x = (t >= o) ? sd[t - o] : 0; __syncthreads();
    sd[t] += x; __syncthreads();
  }
  int pre = sd[t] - tot + bsum[b];
#pragma unroll
  for (int k = 0; k < 4; ++k) { int i = base + k; if (i < n) { rowptr[i] = pre; pre += v[k]; } }
}

__global__ void k_fill(EdgePtrs Eg, const int* rowptr, int* fill, int* asx) {
  int gid = blockIdx.x * blockDim.x + threadIdx.x;
  if (gid >= TOTEDGE) return;
  int r = gid / NEDGE, e = gid - r * NEDGE;
  int d = Eg.d[r][e];
  int seg = c_ADOFF[r] + d;
  int pos = rowptr[seg] + atomicAdd(&fill[seg], 1);
  asx[pos] = Eg.s[r][e];            // LOCAL src index within the relation's src type
}

// ---------------- per-node attention logits: als = act(x)@wv_s, ald = act(x)@wv_d ----------------
struct AlphaP {
  const float* x0; const float* x1; const float* x2; const float* x3;
  float* als; float* ald;
  const float* wvs; const float* wvd;
  int act;
};

__global__ void k_alphas(AlphaP P) {
  int wid = (blockIdx.x * blockDim.x + threadIdx.x) >> 6;
  int lane = threadIdx.x & 63;
  int nw = (gridDim.x * blockDim.x) >> 6;
  for (int row = wid; row < TOTROWS; row += nw) {
    int t = (row >= c_XOFF[1]) + (row >= c_XOFF[2]) + (row >= c_XOFF[3]);
    int n = row - c_XOFF[t];
    const float* xt = t == 0 ? P.x0 : t == 1 ? P.x1 : t == 2 ? P.x2 : P.x3;
    float v = xt[n * 64 + lane];
    if (P.act) v = fmaxf(v, 0.f);
#pragma unroll
    for (int r = 0; r < 9; ++r) {
      if (c_SRC[r] == t) {
        float s = v * P.wvs[r * 64 + lane];
#pragma unroll
        for (int o = 32; o; o >>= 1) s += __shfl_xor(s, o);
        if (lane == 0) P.als[c_ASOFF[r] + n] = s;
      }
      if (c_DST[r] == t) {
        float s = v * P.wvd[r * 64 + lane];
#pragma unroll
        for (int o = 32; o; o >>= 1) s += __shfl_xor(s, o);
        if (lane == 0) P.ald[c_ADOFF[r] + n] = s;
      }
    }
  }
}

// ---------------- xout init: per-type bias presum ----------------
__global__ void k_init(float* xout, const float* bsum) {
  int wid = (blockIdx.x * blockDim.x + threadIdx.x) >> 6;
  int lane = threadIdx.x & 63;
  if (wid >= TOTROWS) return;
  int t = (wid >= c_XOFF[1]) + (wid >= c_XOFF[2]) + (wid >= c_XOFF[3]);
  xout[wid * 64 + lane] = bsum[t * 64 + lane];
}

// ---------------- hs = act(x_src) @ W  (64-row tiles, K=64), one relation ----------------
struct GemmP { const float* x; const float* W; float* hs; int Ns; int act; };

__global__ __launch_bounds__(256) void k_gemm(GemmP G) {
  __shared__ float xs[64 * 65];
  __shared__ float ws[64 * 64];
  int base = blockIdx.x * 64;
  int tid = threadIdx.x;
  for (int k = tid; k < 1024; k += 256)
    ((float4*)ws)[k] = ((const float4*)G.W)[k];
  for (int k = tid; k < 1024; k += 256) {
    int row = k >> 4;
    int col = (k & 15) * 4;
    int gr = base + row;
    float4 v = make_float4(0.f, 0.f, 0.f, 0.f);
    if (gr < G.Ns) v = ((const float4*)G.x)[gr * 16 + (k & 15)];
    if (G.act) { v.x = fmaxf(v.x, 0.f); v.y = fmaxf(v.y, 0.f); v.z = fmaxf(v.z, 0.f); v.w = fmaxf(v.w, 0.f); }
    float* dst = &xs[row * 65 + col];
    dst[0] = v.x; dst[1] = v.y; dst[2] = v.z; dst[3] = v.w;
  }
  __syncthreads();
  int ty = tid >> 4, tx = tid & 15;
  float acc[4][4] = {};
#pragma unroll 8
  for (int j = 0; j < 64; ++j) {
    float4 wv = *(const float4*)&ws[j * 64 + tx * 4];
#pragma unroll
    for (int ri = 0; ri < 4; ++ri) {
      float xv = xs[(ty + 16 * ri) * 65 + j];
      acc[ri][0] = fmaf(xv, wv.x, acc[ri][0]);
      acc[ri][1] = fmaf(xv, wv.y, acc[ri][1]);
      acc[ri][2] = fmaf(xv, wv.z, acc[ri][2]);
      acc[ri][3] = fmaf(xv, wv.w, acc[ri][3]);
    }
  }
#pragma unroll
  for (int ri = 0; ri < 4; ++ri) {
    int lr = base + ty + 16 * ri;
    if (lr < G.Ns) {
      float4 o = make_float4(acc[ri][0], acc[ri][1], acc[ri][2], acc[ri][3]);
      *(float4*)&G.hs[lr * 64 + tx * 4] = o;
    }
  }
}

// ---------------- fused segment softmax + aggregate for ONE relation ----------------
// one wave per dst node; xout[node] += sum(alpha * hs[src]); no atomics.
struct AggP {
  const float* hs; const float* als; const float* ald;
  const int* rowptr; const int* asx;
  float* xout;                 // already offset to this dst type's base
  int Nd; int asoff; int adoff;
};

__global__ void k_agg(AggP A) {
  int wid = (blockIdx.x * blockDim.x + threadIdx.x) >> 6;
  int lane = threadIdx.x & 63;
  if (wid >= A.Nd) return;
  int seg = A.adoff + wid;
  int p0 = A.rowptr[seg], p1 = A.rowptr[seg + 1];
  int deg = p1 - p0;
  if (deg <= 0) return;
  float aldv = A.ald[seg];
  // phase 1: segment max (exact, matches reference)
  float mymax = -3.4e38f;
  for (int i = lane; i < deg; i += 64) {
    float s = A.als[A.asoff + A.asx[p0 + i]] + aldv;
    s = s >= 0.f ? s : 0.2f * s;
    mymax = fmaxf(mymax, s);
  }
#pragma unroll
  for (int o = 32; o; o >>= 1) mymax = fmaxf(mymax, __shfl_xor(mymax, o));
  // phase 2: z = sum exp(s - m)
  float myz = 0.f;
  for (int i = lane; i < deg; i += 64) {
    float s = A.als[A.asoff + A.asx[p0 + i]] + aldv;
    s = s >= 0.f ? s : 0.2f * s;
    myz += __expf(s - mymax);
  }
#pragma unroll
  for (int o = 32; o; o >>= 1) myz += __shfl_xor(myz, o);
  float rz = 1.f / (myz + 1e-16f);
  // phase 3: acc += alpha * hs[src]  (H across lanes)
  float acc = 0.f;
  for (int j = 0; j < deg; ++j) {
    int ls = A.asx[p0 + j];
    float s = A.als[A.asoff + ls] + aldv;
    s = s >= 0.f ? s : 0.2f * s;
    float alpha = __expf(s - mymax) * rz;
    acc = fmaf(alpha, A.hs[ls * 64 + lane], acc);
  }
  A.xout[(size_t)wid * 64 + lane] += acc;
}

// ---------------- pooling: seg-mean of relu(x) over sorted batch ----------------
__global__ void k_pool(const float* xfin, const int* bvar, const int* bcon, float* pool) {
  int wid = (blockIdx.x * blockDim.x + threadIdx.x) >> 6;
  int lane = threadIdx.x & 63;
  int nw = (gridDim.x * blockDim.x) >> 6;
  const int TOT = 180000;
  int per = (TOT + nw - 1) / nw;
  int st = wid * per;
  int en = st + per; if (en > TOT) en = TOT;
  float acc = 0.f, crn = 0.f;
  int ct = -1, cg = -1;
  for (int i = st; i < en; ++i) {
    int t, n; const int* batch;
    if (i < 100000) { t = 0; n = i; batch = bvar; }
    else            { t = 3; n = i - 100000; batch = bcon; }
    int g = batch[n];
    if (t != ct || g != cg) {
      if (ct >= 0) {
        atomicAdd(&pool[(ct ? 4096 : 0) + cg * 64 + lane], acc);
        if (lane == 0) atomicAdd(&pool[8192 + (ct ? 64 : 0) + cg], crn);
      }
      ct = t; cg = g; acc = 0.f; crn = 0.f;
    }
    acc += fmaxf(xfin[(size_t)(c_XOFF[t] + n) * 64 + lane], 0.f);
    crn += 1.f;
  }
  if (ct >= 0) {
    atomicAdd(&pool[(ct ? 4096 : 0) + cg * 64 + lane], acc);
    if (lane == 0) atomicAdd(&pool[8192 + (ct ? 64 : 0) + cg], crn);
  }
}

__global__ void k_final(const float* pool, const float* lin_w, const float* lin_b, float* out) {
  int k = threadIdx.x;          // 128 = 64 graphs x 2 outputs
  int g = k >> 1, o = k & 1;
  float c0 = fmaxf(pool[8192 + g], 1.f);
  float c3 = fmaxf(pool[8256 + g], 1.f);
  float acc = lin_b[o];
  for (int i = 0; i < 64; ++i) {
    acc += (pool[g * 64 + i] / c0) * lin_w[o * 128 + i];
    acc += (pool[4096 + g * 64 + i] / c3) * lin_w[o * 128 + 64 + i];
  }
  out[g * 2 + o] = acc;
}

__global__ void k_bail(float* out) {
  if (threadIdx.x < 128) out[threadIdx.x] = 0.f;
}

// ---------------- host launch ----------------
extern "C" void kernel_launch(void* const* d_in, const int* in_sizes, int n_in,
                              void* d_out, int out_size, void* d_ws, size_t ws_size,
                              hipStream_t stream) {
  (void)in_sizes; (void)n_in; (void)out_size;
  // ---- workspace layout (floats) ----
  const size_t O_XA   = 0;            // 16,000,000
  const size_t O_XB   = 16000000;     // 16,000,000
  const size_t O_HS   = 32000000;     //  6,400,000 (one relation, max 100k rows)
  const size_t O_ALS  = 38400000;     //    660,000
  const size_t O_ALD  = 39060000;     //    660,000
  const size_t O_WV   = 39720000;     //      2,304
  const size_t O_BS   = 39722304;     //        512
  const size_t O_RP   = 39722816;     //    660,016 (int)
  const size_t O_BSC  = 40382832;     //      1,024 (int)
  const size_t O_ASX  = 40383856;     //  2,700,000 (int)
  const size_t O_CNT  = 43083856;     //    660,000 (int)
  const size_t O_FILL = 43743856;     //    660,000 (int)
  const size_t O_POOL = 44403856;     //      8,320
  const size_t NEED   = 44412176;     // floats (~170 MB)

  if (ws_size < NEED * 4) {           // graceful, deterministic bail (diagnostic)
    k_bail<<<1, 128, 0, stream>>>((float*)d_out);
    return;
  }

  const float* x0 = (const float*)d_in[0];
  const float* x1 = (const float*)d_in[1];
  const float* x2 = (const float*)d_in[2];
  const float* x3 = (const float*)d_in[3];
  const float* Wsrc = (const float*)d_in[4];
  const float* Wdst = (const float*)d_in[5];
  const float* asrc = (const float*)d_in[6];
  const float* adst = (const float*)d_in[7];
  const float* bias = (const float*)d_in[8];
  const float* lin_w = (const float*)d_in[9];
  const float* lin_b = (const float*)d_in[10];
  EdgePtrs Eg;
  for (int r = 0; r < 9; ++r) {
    Eg.s[r] = (const int*)d_in[11 + 2 * r];
    Eg.d[r] = (const int*)d_in[12 + 2 * r];
  }
  const int* bvar = (const int*)d_in[29];
  const int* bcon = (const int*)d_in[30];

  float* ws = (float*)d_ws;
  float* xA   = ws + O_XA;
  float* xB   = ws + O_XB;
  float* hs   = ws + O_HS;
  float* als  = ws + O_ALS;
  float* ald  = ws + O_ALD;
  float* wv   = ws + O_WV;
  float* bsum = ws + O_BS;
  int* rowptr = (int*)(ws + O_RP);
  int* bsc    = (int*)(ws + O_BSC);
  int* asx    = (int*)(ws + O_ASX);
  int* cnt    = (int*)(ws + O_CNT);
  int* fill   = (int*)(ws + O_FILL);
  float* pool = ws + O_POOL;

  const int h_NS[4]   = {100000, 20000, 50000, 80000};
  const int h_SRC[9]  = {0,0,0,2,3,1,2,3,3};
  const int h_DST[9]  = {1,2,3,3,3,0,0,0,2};
  const int h_XOFF[4] = {0,100000,120000,170000};
  const int h_ASOFF[9] = {0,100000,200000,300000,350000,430000,450000,500000,580000};
  const int h_ADOFF[9] = {0,20000,70000,150000,230000,310000,410000,510000,610000};

  // zero cnt + fill + pool (cnt and fill are contiguous; pool follows fill)
  hipMemsetAsync(cnt, 0, (size_t)(660000 + 660000 + 8320) * 4, stream);

  k_setup<<<37, 64, 0, stream>>>(Wsrc, Wdst, asrc, adst, bias, wv, bsum);

  // CSR build (layer-independent)
  k_count<<<(TOTEDGE + 255) / 256, 256, 0, stream>>>(Eg, cnt);
  int nb = (TOTSEG + 1023) / 1024;  // 645
  k_scan1<<<nb, 256, 0, stream>>>(cnt, bsc, TOTSEG);
  k_scan2<<<1, 1024, 0, stream>>>(bsc, nb, rowptr, TOTSEG, TOTEDGE);
  k_scan3<<<nb, 256, 0, stream>>>(cnt, bsc, rowptr, TOTSEG);
  k_fill<<<(TOTEDGE + 255) / 256, 256, 0, stream>>>(Eg, rowptr, fill, asx);

  for (int l = 0; l < 2; ++l) {
    const float* xin[4];
    if (l == 0) { xin[0] = x0; xin[1] = x1; xin[2] = x2; xin[3] = x3; }
    else {
      for (int t = 0; t < 4; ++t) xin[t] = xA + (size_t)h_XOFF[t] * 64;
    }
    float* xout = l ? xB : xA;
    int act = (l > 0);

    AlphaP AP;
    AP.x0 = xin[0]; AP.x1 = xin[1]; AP.x2 = xin[2]; AP.x3 = xin[3];
    AP.als = als; AP.ald = ald;
    AP.wvs = wv + l * 576; AP.wvd = wv + 1152 + l * 576;
    AP.act = act;
    k_alphas<<<1024, 256, 0, stream>>>(AP);

    k_init<<<(TOTROWS + 3) / 4, 256, 0, stream>>>(xout, bsum + l * 256);

    for (int r = 0; r < 9; ++r) {
      int st = h_SRC[r], dt = h_DST[r];
      GemmP G;
      G.x = xin[st];
      G.W = Wsrc + ((size_t)l * 9 + r) * 4096;
      G.hs = hs;
      G.Ns = h_NS[st];
      G.act = act;
      int tiles = (G.Ns + 63) / 64;
      k_gemm<<<tiles, 256, 0, stream>>>(G);

      AggP A;
      A.hs = hs; A.als = als; A.ald = ald;
      A.rowptr = rowptr; A.asx = asx;
      A.xout = xout + (size_t)h_XOFF[dt] * 64;
      A.Nd = h_NS[dt]; A.asoff = h_ASOFF[r]; A.adoff = h_ADOFF[r];
      k_agg<<<(A.Nd + 3) / 4, 256, 0, stream>>>(A);
    }
  }

  k_pool<<<512, 256, 0, stream>>>(xB, bvar, bcon, pool);
  k_final<<<1, 128, 0, stream>>>(pool, lin_w, lin_b, (float*)d_out);
}

// Round 3
// 1465.319 us; speedup vs baseline: 1.4758x; 1.4758x over previous
//
#include <hip/hip_runtime.h>

#define NH 64
#define NRELS 9
#define NEDGE 300000
#define NGRAPH 64
#define TOTROWS 250000
#define TOTSEG 660000
#define TOTEDGE (NRELS * NEDGE)

__constant__ int c_NS[4]     = {100000, 20000, 50000, 80000};
__constant__ int c_SRC[9]    = {0,0,0,2,3,1,2,3,3};
__constant__ int c_DST[9]    = {1,2,3,3,3,0,0,0,2};
__constant__ int c_XOFF[5]   = {0,100000,120000,170000,250000};
__constant__ int c_ASOFF[10] = {0,100000,200000,300000,350000,430000,450000,500000,580000,660000};
__constant__ int c_ADOFF[10] = {0,20000,70000,150000,230000,310000,410000,510000,610000,660000};

struct EdgePtrs { const int* s[9]; const int* d[9]; };

// ---------------- setup: wv_s/wv_d = W @ a  (per l,r,side), bias presums ----------------
__global__ void k_setup(const float* Wsrc, const float* Wdst, const float* asrc,
                        const float* adst, const float* bias, float* wv, float* bsum) {
  int b = blockIdx.x, j = threadIdx.x;
  if (b < 36) {
    int r = b % 9, q = b / 9;
    int l = q >> 1, side = q & 1;
    const float* W = (side ? Wdst : Wsrc) + (l * 9 + r) * 64 * 64;
    const float* a = (side ? adst : asrc) + (l * 9 + r) * 64;
    float s = 0.f;
    for (int i = 0; i < 64; ++i) s += W[j * 64 + i] * a[i];
    wv[(side ? 1152 : 0) + (l * 9 + r) * 64 + j] = s;
  } else {
    for (int l = 0; l < 2; ++l)
      for (int t = 0; t < 4; ++t) {
        float s = 0.f;
        for (int r = 0; r < 9; ++r)
          if (c_DST[r] == t) s += bias[(l * 9 + r) * 64 + j];
        bsum[(l * 4 + t) * 64 + j] = s;
      }
  }
}

// ---------------- CSR build over 660k (relation,dst) segments ----------------
__global__ void k_count(EdgePtrs Eg, int* cnt) {
  int gid = blockIdx.x * blockDim.x + threadIdx.x;
  if (gid >= TOTEDGE) return;
  int r = gid / NEDGE, e = gid - r * NEDGE;
  int d = Eg.d[r][e];
  atomicAdd(&cnt[c_ADOFF[r] + d], 1);
}

__global__ void k_scan1(const int* cnt, int* bsum, int n) {
  __shared__ int sd[256];
  int b = blockIdx.x, t = threadIdx.x;
  int base = b * 1024 + t * 4;
  int s = 0;
#pragma unroll
  for (int k = 0; k < 4; ++k) { int i = base + k; if (i < n) s += cnt[i]; }
  sd[t] = s; __syncthreads();
  for (int o = 128; o; o >>= 1) { if (t < o) sd[t] += sd[t + o]; __syncthreads(); }
  if (t == 0) bsum[b] = sd[0];
}

__global__ void k_scan2(int* bsum, int nb, int* rowptr, int n, int total) {
  __shared__ int sd[1024];
  int t = threadIdx.x;
  int v = (t < nb) ? bsum[t] : 0;
  sd[t] = v; __syncthreads();
  for (int o = 1; o < 1024; o <<= 1) {
    int x = (t >= o) ? sd[t - o] : 0; __syncthreads();
    sd[t] += x; __syncthreads();
  }
  if (t < nb) bsum[t] = sd[t] - v;   // exclusive
  if (t == 0) rowptr[n] = total;
}

__global__ void k_scan3(const int* cnt, const int* bsum, int* rowptr, int n) {
  __shared__ int sd[256];
  int b = blockIdx.x, t = threadIdx.x;
  int base = b * 1024 + t * 4;
  int v[4]; int s = 0;
#pragma unroll
  for (int k = 0; k < 4; ++k) { int i = base + k; v[k] = (i < n) ? cnt[i] : 0; s += v[k]; }
  sd[t] = s; __syncthreads();
  int tot = s;
  for (int o = 1; o < 256; o <<= 1) {
    int x = (t >= o) ? sd[t - o] : 0; __syncthreads();
    sd[t] += x; __syncthreads();
  }
  int pre = sd[t] - tot + bsum[b];
#pragma unroll
  for (int k = 0; k < 4; ++k) { int i = base + k; if (i < n) { rowptr[i] = pre; pre += v[k]; } }
}

__global__ void k_fill(EdgePtrs Eg, const int* rowptr, int* fill, int* asx) {
  int gid = blockIdx.x * blockDim.x + threadIdx.x;
  if (gid >= TOTEDGE) return;
  int r = gid / NEDGE, e = gid - r * NEDGE;
  int d = Eg.d[r][e];
  int seg = c_ADOFF[r] + d;
  int pos = rowptr[seg] + atomicAdd(&fill[seg], 1);
  asx[pos] = Eg.s[r][e];            // LOCAL src index within the relation's src type
}

// ---------------- per-node attention logits, thread-per-node, no shuffles ----------------
struct AlphaP {
  const float* x0; const float* x1; const float* x2; const float* x3;
  float* als; float* ald;
  const float* wvs; const float* wvd;   // [9][64] each, this layer
  int act; int smask; int dmask;
};

__global__ __launch_bounds__(256) void k_alphas(AlphaP P) {
  __shared__ float sws[576];
  __shared__ float swd[576];
  for (int i = threadIdx.x; i < 576; i += 256) { sws[i] = P.wvs[i]; swd[i] = P.wvd[i]; }
  __syncthreads();
  int node = blockIdx.x * 256 + threadIdx.x;
  if (node >= TOTROWS) return;
  int t = (node >= c_XOFF[1]) + (node >= c_XOFF[2]) + (node >= c_XOFF[3]);
  int n = node - c_XOFF[t];
  const float* xt = t == 0 ? P.x0 : t == 1 ? P.x1 : t == 2 ? P.x2 : P.x3;
  const float4* rp = (const float4*)xt + (size_t)n * 16;
  float4 row[16];
#pragma unroll
  for (int k = 0; k < 16; ++k) row[k] = rp[k];
  if (P.act) {
#pragma unroll
    for (int k = 0; k < 16; ++k) {
      row[k].x = fmaxf(row[k].x, 0.f); row[k].y = fmaxf(row[k].y, 0.f);
      row[k].z = fmaxf(row[k].z, 0.f); row[k].w = fmaxf(row[k].w, 0.f);
    }
  }
#pragma unroll
  for (int r = 0; r < 9; ++r) {
    bool ns = ((P.smask >> r) & 1) && (c_SRC[r] == t);
    bool nd = ((P.dmask >> r) & 1) && (c_DST[r] == t);
    if (ns) {
      float s = 0.f;
#pragma unroll
      for (int k = 0; k < 16; ++k) {
        float4 w = *(const float4*)&sws[r * 64 + k * 4];
        s += row[k].x * w.x + row[k].y * w.y + row[k].z * w.z + row[k].w * w.w;
      }
      P.als[c_ASOFF[r] + n] = s;
    }
    if (nd) {
      float s = 0.f;
#pragma unroll
      for (int k = 0; k < 16; ++k) {
        float4 w = *(const float4*)&swd[r * 64 + k * 4];
        s += row[k].x * w.x + row[k].y * w.y + row[k].z * w.z + row[k].w * w.w;
      }
      P.ald[c_ADOFF[r] + n] = s;
    }
  }
}

// ---------------- xout init: per-type bias presum ----------------
__global__ void k_init(float* xout, const float* bsum, int full) {
  int wid = (blockIdx.x * blockDim.x + threadIdx.x) >> 6;
  int lane = threadIdx.x & 63;
  if (full) { if (wid >= TOTROWS) return; }
  else {
    if (wid >= 180000) return;
    wid = wid < 100000 ? wid : wid + 70000;   // types 0 and 3 only
  }
  int t = (wid >= c_XOFF[1]) + (wid >= c_XOFF[2]) + (wid >= c_XOFF[3]);
  xout[(size_t)wid * 64 + lane] = bsum[t * 64 + lane];
}

// ---------------- hs = act(x_src) @ W  (64-row tiles, K=64), one relation ----------------
struct GemmP { const float* x; const float* W; float* hs; int Ns; int act; };

__global__ __launch_bounds__(256) void k_gemm(GemmP G) {
  __shared__ float xs[64 * 65];
  __shared__ float ws[64 * 64];
  int base = blockIdx.x * 64;
  int tid = threadIdx.x;
  for (int k = tid; k < 1024; k += 256)
    ((float4*)ws)[k] = ((const float4*)G.W)[k];
  for (int k = tid; k < 1024; k += 256) {
    int row = k >> 4;
    int col = (k & 15) * 4;
    int gr = base + row;
    float4 v = make_float4(0.f, 0.f, 0.f, 0.f);
    if (gr < G.Ns) v = ((const float4*)G.x)[gr * 16 + (k & 15)];
    if (G.act) { v.x = fmaxf(v.x, 0.f); v.y = fmaxf(v.y, 0.f); v.z = fmaxf(v.z, 0.f); v.w = fmaxf(v.w, 0.f); }
    float* dst = &xs[row * 65 + col];
    dst[0] = v.x; dst[1] = v.y; dst[2] = v.z; dst[3] = v.w;
  }
  __syncthreads();
  int ty = tid >> 4, tx = tid & 15;
  float acc[4][4] = {};
#pragma unroll 8
  for (int j = 0; j < 64; ++j) {
    float4 wv = *(const float4*)&ws[j * 64 + tx * 4];
#pragma unroll
    for (int ri = 0; ri < 4; ++ri) {
      float xv = xs[(ty + 16 * ri) * 65 + j];
      acc[ri][0] = fmaf(xv, wv.x, acc[ri][0]);
      acc[ri][1] = fmaf(xv, wv.y, acc[ri][1]);
      acc[ri][2] = fmaf(xv, wv.z, acc[ri][2]);
      acc[ri][3] = fmaf(xv, wv.w, acc[ri][3]);
    }
  }
#pragma unroll
  for (int ri = 0; ri < 4; ++ri) {
    int lr = base + ty + 16 * ri;
    if (lr < G.Ns) {
      float4 o = make_float4(acc[ri][0], acc[ri][1], acc[ri][2], acc[ri][3]);
      *(float4*)&G.hs[lr * 64 + tx * 4] = o;
    }
  }
}

// ---------------- fused online segment softmax + aggregate for ONE relation ----------------
struct AggP {
  const float* hs; const float* als; const float* ald;
  const int* rowptr; const int* asx;
  float* xout;                 // already offset to this dst type's base
  float* esc;                  // per-edge score scratch (this relation, 300k)
  int Nd; int asoff; int adoff; int ebase;
};

__global__ void k_agg(AggP A) {
  int wid = (blockIdx.x * blockDim.x + threadIdx.x) >> 6;
  int lane = threadIdx.x & 63;
  if (wid >= A.Nd) return;
  int seg = A.adoff + wid;
  int p0 = A.rowptr[seg], p1 = A.rowptr[seg + 1];
  int deg = p1 - p0;
  if (deg <= 0) return;
  float aldv = A.ald[seg];
  float* escp = A.esc + (p0 - A.ebase);
  // online softmax: one pass for (max, sum), stashing scores
  float m = -3.4e38f, z = 0.f;
  for (int i = lane; i < deg; i += 64) {
    float s = A.als[A.asoff + A.asx[p0 + i]] + aldv;
    s = s >= 0.f ? s : 0.2f * s;
    escp[i] = s;
    float mn = fmaxf(m, s);
    z = z * __expf(m - mn) + __expf(s - mn);
    m = mn;
  }
#pragma unroll
  for (int o = 32; o; o >>= 1) {
    float mo = __shfl_xor(m, o), zo = __shfl_xor(z, o);
    float mn = fmaxf(m, mo);
    z = z * __expf(m - mn) + zo * __expf(mo - mn);
    m = mn;
  }
  float rz = 1.f / (z + 1e-16f);
  // weighted gather: coalesced chunk loads + shfl broadcast
  float acc = 0.f;
  for (int c0 = 0; c0 < deg; c0 += 64) {
    int cn = deg - c0; if (cn > 64) cn = 64;
    int ls = 0; float al = 0.f;
    if (lane < cn) {
      ls = A.asx[p0 + c0 + lane];
      al = __expf(escp[c0 + lane] - m) * rz;
    }
    for (int j = 0; j < cn; ++j) {
      int lsj = __shfl(ls, j);
      float aj = __shfl(al, j);
      acc = fmaf(aj, A.hs[(size_t)lsj * 64 + lane], acc);
    }
  }
  A.xout[(size_t)wid * 64 + lane] += acc;
}

// ---------------- pooling: seg-mean of relu(x) over sorted batch ----------------
__global__ void k_pool(const float* xfin, const int* bvar, const int* bcon, float* pool) {
  int wid = (blockIdx.x * blockDim.x + threadIdx.x) >> 6;
  int lane = threadIdx.x & 63;
  int nw = (gridDim.x * blockDim.x) >> 6;
  const int TOT = 180000;
  int per = (TOT + nw - 1) / nw;
  int st = wid * per;
  int en = st + per; if (en > TOT) en = TOT;
  float acc = 0.f, crn = 0.f;
  int ct = -1, cg = -1;
  for (int i = st; i < en; ++i) {
    int t, n; const int* batch;
    if (i < 100000) { t = 0; n = i; batch = bvar; }
    else            { t = 3; n = i - 100000; batch = bcon; }
    int g = batch[n];
    if (t != ct || g != cg) {
      if (ct >= 0) {
        atomicAdd(&pool[(ct ? 4096 : 0) + cg * 64 + lane], acc);
        if (lane == 0) atomicAdd(&pool[8192 + (ct ? 64 : 0) + cg], crn);
      }
      ct = t; cg = g; acc = 0.f; crn = 0.f;
    }
    acc += fmaxf(xfin[(size_t)(c_XOFF[t] + n) * 64 + lane], 0.f);
    crn += 1.f;
  }
  if (ct >= 0) {
    atomicAdd(&pool[(ct ? 4096 : 0) + cg * 64 + lane], acc);
    if (lane == 0) atomicAdd(&pool[8192 + (ct ? 64 : 0) + cg], crn);
  }
}

__global__ void k_final(const float* pool, const float* lin_w, const float* lin_b, float* out) {
  int k = threadIdx.x;          // 128 = 64 graphs x 2 outputs
  int g = k >> 1, o = k & 1;
  float c0 = fmaxf(pool[8192 + g], 1.f);
  float c3 = fmaxf(pool[8256 + g], 1.f);
  float acc = lin_b[o];
  for (int i = 0; i < 64; ++i) {
    acc += (pool[g * 64 + i] / c0) * lin_w[o * 128 + i];
    acc += (pool[4096 + g * 64 + i] / c3) * lin_w[o * 128 + 64 + i];
  }
  out[g * 2 + o] = acc;
}

__global__ void k_bail(float* out) {
  if (threadIdx.x < 128) out[threadIdx.x] = 0.f;
}

// ---------------- host launch ----------------
extern "C" void kernel_launch(void* const* d_in, const int* in_sizes, int n_in,
                              void* d_out, int out_size, void* d_ws, size_t ws_size,
                              hipStream_t stream) {
  (void)in_sizes; (void)n_in; (void)out_size;
  // ---- workspace layout (floats) ----
  const size_t O_XA   = 0;            // 16,000,000
  const size_t O_XB   = 16000000;     // 16,000,000
  const size_t O_HS   = 32000000;     //  6,400,000 (one relation, max 100k rows)
  const size_t O_ALS  = 38400000;     //    660,000
  const size_t O_ALD  = 39060000;     //    660,000
  const size_t O_WV   = 39720000;     //      2,304
  const size_t O_BS   = 39722304;     //        512
  const size_t O_RP   = 39722816;     //    660,016 (int)
  const size_t O_BSC  = 40382832;     //      1,024 (int)
  const size_t O_ASX  = 40383856;     //  2,700,000 (int)
  const size_t O_CNT  = 43083856;     //    660,000 (int)  — reused as esc after CSR build
  const size_t O_FILL = 43743856;     //    660,000 (int)
  const size_t O_POOL = 44403856;     //      8,320
  const size_t NEED   = 44412176;     // floats (~178 MB)

  if (ws_size < NEED * 4) {           // graceful, deterministic bail (diagnostic)
    k_bail<<<1, 128, 0, stream>>>((float*)d_out);
    return;
  }

  const float* x0 = (const float*)d_in[0];
  const float* x1 = (const float*)d_in[1];
  const float* x2 = (const float*)d_in[2];
  const float* x3 = (const float*)d_in[3];
  const float* Wsrc = (const float*)d_in[4];
  const float* Wdst = (const float*)d_in[5];
  const float* asrc = (const float*)d_in[6];
  const float* adst = (const float*)d_in[7];
  const float* bias = (const float*)d_in[8];
  const float* lin_w = (const float*)d_in[9];
  const float* lin_b = (const float*)d_in[10];
  EdgePtrs Eg;
  for (int r = 0; r < 9; ++r) {
    Eg.s[r] = (const int*)d_in[11 + 2 * r];
    Eg.d[r] = (const int*)d_in[12 + 2 * r];
  }
  const int* bvar = (const int*)d_in[29];
  const int* bcon = (const int*)d_in[30];

  float* ws = (float*)d_ws;
  float* xA   = ws + O_XA;
  float* xB   = ws + O_XB;
  float* hs   = ws + O_HS;
  float* als  = ws + O_ALS;
  float* ald  = ws + O_ALD;
  float* wv   = ws + O_WV;
  float* bsum = ws + O_BS;
  int* rowptr = (int*)(ws + O_RP);
  int* bsc    = (int*)(ws + O_BSC);
  int* asx    = (int*)(ws + O_ASX);
  int* cnt    = (int*)(ws + O_CNT);
  int* fill   = (int*)(ws + O_FILL);
  float* esc  = ws + O_CNT;           // alias: cnt dead after CSR build
  float* pool = ws + O_POOL;

  const int h_NS[4]   = {100000, 20000, 50000, 80000};
  const int h_SRC[9]  = {0,0,0,2,3,1,2,3,3};
  const int h_DST[9]  = {1,2,3,3,3,0,0,0,2};
  const int h_XOFF[4] = {0,100000,120000,170000};
  const int h_ASOFF[9] = {0,100000,200000,300000,350000,430000,450000,500000,580000};
  const int h_ADOFF[9] = {0,20000,70000,150000,230000,310000,410000,510000,610000};

  // zero cnt + fill + pool (contiguous)
  hipMemsetAsync(cnt, 0, (size_t)(660000 + 660000 + 8320) * 4, stream);

  k_setup<<<37, 64, 0, stream>>>(Wsrc, Wdst, asrc, adst, bias, wv, bsum);

  // CSR build (layer-independent)
  k_count<<<(TOTEDGE + 255) / 256, 256, 0, stream>>>(Eg, cnt);
  int nb = (TOTSEG + 1023) / 1024;  // 645
  k_scan1<<<nb, 256, 0, stream>>>(cnt, bsc, TOTSEG);
  k_scan2<<<1, 1024, 0, stream>>>(bsc, nb, rowptr, TOTSEG, TOTEDGE);
  k_scan3<<<nb, 256, 0, stream>>>(cnt, bsc, rowptr, TOTSEG);
  k_fill<<<(TOTEDGE + 255) / 256, 256, 0, stream>>>(Eg, rowptr, fill, asx);

  for (int l = 0; l < 2; ++l) {
    const float* xin[4];
    if (l == 0) { xin[0] = x0; xin[1] = x1; xin[2] = x2; xin[3] = x3; }
    else {
      for (int t = 0; t < 4; ++t) xin[t] = xA + (size_t)h_XOFF[t] * 64;
    }
    float* xout = l ? xB : xA;
    int act = (l > 0);
    int relmask = l ? 0x0FC : 0x1FF;   // layer 2: dst types 1,2 unused -> skip r0,r1,r8

    AlphaP AP;
    AP.x0 = xin[0]; AP.x1 = xin[1]; AP.x2 = xin[2]; AP.x3 = xin[3];
    AP.als = als; AP.ald = ald;
    AP.wvs = wv + l * 576; AP.wvd = wv + 1152 + l * 576;
    AP.act = act; AP.smask = relmask; AP.dmask = relmask;
    k_alphas<<<(TOTROWS + 255) / 256, 256, 0, stream>>>(AP);

    int initw = l ? 180000 : TOTROWS;
    k_init<<<(initw + 3) / 4, 256, 0, stream>>>(xout, bsum + l * 256, l == 0);

    for (int r = 0; r < 9; ++r) {
      if (!((relmask >> r) & 1)) continue;
      int st = h_SRC[r], dt = h_DST[r];
      GemmP G;
      G.x = xin[st];
      G.W = Wsrc + ((size_t)l * 9 + r) * 4096;
      G.hs = hs;
      G.Ns = h_NS[st];
      G.act = act;
      int tiles = (G.Ns + 63) / 64;
      k_gemm<<<tiles, 256, 0, stream>>>(G);

      AggP A;
      A.hs = hs; A.als = als; A.ald = ald;
      A.rowptr = rowptr; A.asx = asx;
      A.xout = xout + (size_t)h_XOFF[dt] * 64;
      A.esc = esc;
      A.Nd = h_NS[dt]; A.asoff = h_ASOFF[r]; A.adoff = h_ADOFF[r];
      A.ebase = r * NEDGE;
      k_agg<<<(A.Nd + 3) / 4, 256, 0, stream>>>(A);
    }
  }

  k_pool<<<512, 256, 0, stream>>>(xB, bvar, bcon, pool);
  k_final<<<1, 128, 0, stream>>>(pool, lin_w, lin_b, (float*)d_out);
}

// Round 4
// 1195.602 us; speedup vs baseline: 1.8087x; 1.2256x over previous
//
#include <hip/hip_runtime.h>
#include <hip/hip_bf16.h>

#define NH 64
#define NRELS 9
#define NEDGE 300000
#define NGRAPH 64
#define TOTROWS 250000
#define TOTSEG 660000
#define TOTEDGE (NRELS * NEDGE)

__constant__ int c_NS[4]     = {100000, 20000, 50000, 80000};
__constant__ int c_SRC[9]    = {0,0,0,2,3,1,2,3,3};
__constant__ int c_DST[9]    = {1,2,3,3,3,0,0,0,2};
__constant__ int c_XOFF[5]   = {0,100000,120000,170000,250000};
__constant__ int c_ASOFF[10] = {0,100000,200000,300000,350000,430000,450000,500000,580000,660000};
__constant__ int c_ADOFF[10] = {0,20000,70000,150000,230000,310000,410000,510000,610000,660000};

struct EdgePtrs { const int* s[9]; const int* d[9]; };

// ---------------- setup: wv_s/wv_d = W @ a  (per l,r,side), bias presums ----------------
__global__ void k_setup(const float* Wsrc, const float* Wdst, const float* asrc,
                        const float* adst, const float* bias, float* wv, float* bsum) {
  int b = blockIdx.x, j = threadIdx.x;
  if (b < 36) {
    int r = b % 9, q = b / 9;
    int l = q >> 1, side = q & 1;
    const float* W = (side ? Wdst : Wsrc) + (l * 9 + r) * 64 * 64;
    const float* a = (side ? adst : asrc) + (l * 9 + r) * 64;
    float s = 0.f;
    for (int i = 0; i < 64; ++i) s += W[j * 64 + i] * a[i];
    wv[(side ? 1152 : 0) + (l * 9 + r) * 64 + j] = s;
  } else {
    for (int l = 0; l < 2; ++l)
      for (int t = 0; t < 4; ++t) {
        float s = 0.f;
        for (int r = 0; r < 9; ++r)
          if (c_DST[r] == t) s += bias[(l * 9 + r) * 64 + j];
        bsum[(l * 4 + t) * 64 + j] = s;
      }
  }
}

// ---------------- CSR build over 660k (relation,dst) segments ----------------
__global__ void k_count(EdgePtrs Eg, int* cnt) {
  int gid = blockIdx.x * blockDim.x + threadIdx.x;
  if (gid >= TOTEDGE) return;
  int r = gid / NEDGE, e = gid - r * NEDGE;
  int d = Eg.d[r][e];
  atomicAdd(&cnt[c_ADOFF[r] + d], 1);
}

__global__ void k_scan1(const int* cnt, int* bsum, int n) {
  __shared__ int sd[256];
  int b = blockIdx.x, t = threadIdx.x;
  int base = b * 1024 + t * 4;
  int s = 0;
#pragma unroll
  for (int k = 0; k < 4; ++k) { int i = base + k; if (i < n) s += cnt[i]; }
  sd[t] = s; __syncthreads();
  for (int o = 128; o; o >>= 1) { if (t < o) sd[t] += sd[t + o]; __syncthreads(); }
  if (t == 0) bsum[b] = sd[0];
}

__global__ void k_scan2(int* bsum, int nb, int* rowptr, int n, int total) {
  __shared__ int sd[1024];
  int t = threadIdx.x;
  int v = (t < nb) ? bsum[t] : 0;
  sd[t] = v; __syncthreads();
  for (int o = 1; o < 1024; o <<= 1) {
    int x = (t >= o) ? sd[t - o] : 0; __syncthreads();
    sd[t] += x; __syncthreads();
  }
  if (t < nb) bsum[t] = sd[t] - v;   // exclusive
  if (t == 0) rowptr[n] = total;
}

__global__ void k_scan3(const int* cnt, const int* bsum, int* rowptr, int n) {
  __shared__ int sd[256];
  int b = blockIdx.x, t = threadIdx.x;
  int base = b * 1024 + t * 4;
  int v[4]; int s = 0;
#pragma unroll
  for (int k = 0; k < 4; ++k) { int i = base + k; v[k] = (i < n) ? cnt[i] : 0; s += v[k]; }
  sd[t] = s; __syncthreads();
  int tot = s;
  for (int o = 1; o < 256; o <<= 1) {
    int x = (t >= o) ? sd[t - o] : 0; __syncthreads();
    sd[t] += x; __syncthreads();
  }
  int pre = sd[t] - tot + bsum[b];
#pragma unroll
  for (int k = 0; k < 4; ++k) { int i = base + k; if (i < n) { rowptr[i] = pre; pre += v[k]; } }
}

__global__ void k_fill(EdgePtrs Eg, const int* rowptr, int* fill, int* asx) {
  int gid = blockIdx.x * blockDim.x + threadIdx.x;
  if (gid >= TOTEDGE) return;
  int r = gid / NEDGE, e = gid - r * NEDGE;
  int d = Eg.d[r][e];
  int seg = c_ADOFF[r] + d;
  int pos = rowptr[seg] + atomicAdd(&fill[seg], 1);
  asx[pos] = Eg.s[r][e];            // LOCAL src index within the relation's src type
}

// ---------------- per-node attention logits, thread-per-node, no shuffles ----------------
struct AlphaP {
  const float* x0; const float* x1; const float* x2; const float* x3;
  float* als; float* ald;
  const float* wvs; const float* wvd;   // [9][64] each, this layer
  int act; int smask; int dmask;
};

__global__ __launch_bounds__(256) void k_alphas(AlphaP P) {
  __shared__ float sws[576];
  __shared__ float swd[576];
  for (int i = threadIdx.x; i < 576; i += 256) { sws[i] = P.wvs[i]; swd[i] = P.wvd[i]; }
  __syncthreads();
  int node = blockIdx.x * 256 + threadIdx.x;
  if (node >= TOTROWS) return;
  int t = (node >= c_XOFF[1]) + (node >= c_XOFF[2]) + (node >= c_XOFF[3]);
  int n = node - c_XOFF[t];
  const float* xt = t == 0 ? P.x0 : t == 1 ? P.x1 : t == 2 ? P.x2 : P.x3;
  const float4* rp = (const float4*)xt + (size_t)n * 16;
  float4 row[16];
#pragma unroll
  for (int k = 0; k < 16; ++k) row[k] = rp[k];
  if (P.act) {
#pragma unroll
    for (int k = 0; k < 16; ++k) {
      row[k].x = fmaxf(row[k].x, 0.f); row[k].y = fmaxf(row[k].y, 0.f);
      row[k].z = fmaxf(row[k].z, 0.f); row[k].w = fmaxf(row[k].w, 0.f);
    }
  }
#pragma unroll
  for (int r = 0; r < 9; ++r) {
    bool ns = ((P.smask >> r) & 1) && (c_SRC[r] == t);
    bool nd = ((P.dmask >> r) & 1) && (c_DST[r] == t);
    if (ns) {
      float s = 0.f;
#pragma unroll
      for (int k = 0; k < 16; ++k) {
        float4 w = *(const float4*)&sws[r * 64 + k * 4];
        s += row[k].x * w.x + row[k].y * w.y + row[k].z * w.z + row[k].w * w.w;
      }
      P.als[c_ASOFF[r] + n] = s;
    }
    if (nd) {
      float s = 0.f;
#pragma unroll
      for (int k = 0; k < 16; ++k) {
        float4 w = *(const float4*)&swd[r * 64 + k * 4];
        s += row[k].x * w.x + row[k].y * w.y + row[k].z * w.z + row[k].w * w.w;
      }
      P.ald[c_ADOFF[r] + n] = s;
    }
  }
}

// ---------------- xout init: per-type bias presum ----------------
__global__ void k_init(float* xout, const float* bsum, int full) {
  int wid = (blockIdx.x * blockDim.x + threadIdx.x) >> 6;
  int lane = threadIdx.x & 63;
  if (full) { if (wid >= TOTROWS) return; }
  else {
    if (wid >= 180000) return;
    wid = wid < 100000 ? wid : wid + 70000;   // types 0 and 3 only
  }
  int t = (wid >= c_XOFF[1]) + (wid >= c_XOFF[2]) + (wid >= c_XOFF[3]);
  xout[(size_t)wid * 64 + lane] = bsum[t * 64 + lane];
}

// ---------------- hs = act(x_src) @ W  (64-row tiles, K=64) -> bf16, one relation ----------------
struct GemmP { const float* x; const float* W; __hip_bfloat16* hs; int Ns; int act; };

__global__ __launch_bounds__(256) void k_gemm(GemmP G) {
  __shared__ float xs[64 * 65];
  __shared__ float ws[64 * 64];
  int base = blockIdx.x * 64;
  int tid = threadIdx.x;
  for (int k = tid; k < 1024; k += 256)
    ((float4*)ws)[k] = ((const float4*)G.W)[k];
  for (int k = tid; k < 1024; k += 256) {
    int row = k >> 4;
    int col = (k & 15) * 4;
    int gr = base + row;
    float4 v = make_float4(0.f, 0.f, 0.f, 0.f);
    if (gr < G.Ns) v = ((const float4*)G.x)[gr * 16 + (k & 15)];
    if (G.act) { v.x = fmaxf(v.x, 0.f); v.y = fmaxf(v.y, 0.f); v.z = fmaxf(v.z, 0.f); v.w = fmaxf(v.w, 0.f); }
    float* dst = &xs[row * 65 + col];
    dst[0] = v.x; dst[1] = v.y; dst[2] = v.z; dst[3] = v.w;
  }
  __syncthreads();
  int ty = tid >> 4, tx = tid & 15;
  float acc[4][4] = {};
#pragma unroll 8
  for (int j = 0; j < 64; ++j) {
    float4 wv = *(const float4*)&ws[j * 64 + tx * 4];
#pragma unroll
    for (int ri = 0; ri < 4; ++ri) {
      float xv = xs[(ty + 16 * ri) * 65 + j];
      acc[ri][0] = fmaf(xv, wv.x, acc[ri][0]);
      acc[ri][1] = fmaf(xv, wv.y, acc[ri][1]);
      acc[ri][2] = fmaf(xv, wv.z, acc[ri][2]);
      acc[ri][3] = fmaf(xv, wv.w, acc[ri][3]);
    }
  }
#pragma unroll
  for (int ri = 0; ri < 4; ++ri) {
    int lr = base + ty + 16 * ri;
    if (lr < G.Ns) {
      union { ushort4 u; __hip_bfloat16 h[4]; } cv;
      cv.h[0] = __float2bfloat16(acc[ri][0]);
      cv.h[1] = __float2bfloat16(acc[ri][1]);
      cv.h[2] = __float2bfloat16(acc[ri][2]);
      cv.h[3] = __float2bfloat16(acc[ri][3]);
      *(ushort4*)&G.hs[(size_t)lr * 64 + tx * 4] = cv.u;
    }
  }
}

// ---------------- fused online segment softmax + aggregate for ONE relation ----------------
// 32 lanes per dst node (2 nodes per wave); hs gathered as bf16x2 per lane.
struct AggP {
  const __hip_bfloat16* hs; const float* als; const float* ald;
  const int* rowptr; const int* asx;
  float* xout;                 // already offset to this dst type's base
  float* esc;                  // per-edge score scratch (this relation, 300k)
  int Nd; int asoff; int adoff; int ebase;
};

__global__ void k_agg(AggP A) {
  int gwid = (blockIdx.x * blockDim.x + threadIdx.x) >> 6;  // wave id
  int lane = threadIdx.x & 63;
  int half = lane >> 5;
  int sl   = lane & 31;
  int node = gwid * 2 + half;
  if (node < A.Nd) {
    int seg = A.adoff + node;
    int p0 = A.rowptr[seg], p1 = A.rowptr[seg + 1];
    int deg = p1 - p0;
    if (deg > 0) {
      float aldv = A.ald[seg];
      float* escp = A.esc + (p0 - A.ebase);
      // online softmax over this node's edges (32-lane strided), stash scores
      float m = -3.4e38f, z = 0.f;
      for (int i = sl; i < deg; i += 32) {
        float s = A.als[A.asoff + A.asx[p0 + i]] + aldv;
        s = s >= 0.f ? s : 0.2f * s;
        escp[i] = s;
        float mn = fmaxf(m, s);
        z = z * __expf(m - mn) + __expf(s - mn);
        m = mn;
      }
#pragma unroll
      for (int o = 16; o; o >>= 1) {
        float mo = __shfl_xor(m, o, 32), zo = __shfl_xor(z, o, 32);
        float mn = fmaxf(m, mo);
        z = z * __expf(m - mn) + zo * __expf(mo - mn);
        m = mn;
      }
      float rz = 1.f / (z + 1e-16f);
      // weighted gather: lane loads 2 bf16 cols; 32-chunk edge loads + shfl broadcast
      float accx = 0.f, accy = 0.f;
      for (int c0 = 0; c0 < deg; c0 += 32) {
        int cn = deg - c0; if (cn > 32) cn = 32;
        int ls = 0; float al = 0.f;
        if (sl < cn) {
          ls = A.asx[p0 + c0 + sl];
          al = __expf(escp[c0 + sl] - m) * rz;
        }
        for (int j = 0; j < cn; ++j) {
          int lsj = __shfl(ls, j, 32);
          float aj = __shfl(al, j, 32);
          unsigned hv = *(const unsigned*)&A.hs[(size_t)lsj * 64 + sl * 2];
          float h0 = __uint_as_float(hv << 16);
          float h1 = __uint_as_float(hv & 0xffff0000u);
          accx = fmaf(aj, h0, accx);
          accy = fmaf(aj, h1, accy);
        }
      }
      float2* xo = (float2*)&A.xout[(size_t)node * 64 + sl * 2];
      float2 cur = *xo;
      cur.x += accx; cur.y += accy;
      *xo = cur;
    }
  }
}

// ---------------- pooling: seg-mean of relu(x) over sorted batch ----------------
__global__ void k_pool(const float* xfin, const int* bvar, const int* bcon, float* pool) {
  int wid = (blockIdx.x * blockDim.x + threadIdx.x) >> 6;
  int lane = threadIdx.x & 63;
  int nw = (gridDim.x * blockDim.x) >> 6;
  const int TOT = 180000;
  int per = (TOT + nw - 1) / nw;
  int st = wid * per;
  int en = st + per; if (en > TOT) en = TOT;
  float acc = 0.f, crn = 0.f;
  int ct = -1, cg = -1;
  for (int i = st; i < en; ++i) {
    int t, n; const int* batch;
    if (i < 100000) { t = 0; n = i; batch = bvar; }
    else            { t = 3; n = i - 100000; batch = bcon; }
    int g = batch[n];
    if (t != ct || g != cg) {
      if (ct >= 0) {
        atomicAdd(&pool[(ct ? 4096 : 0) + cg * 64 + lane], acc);
        if (lane == 0) atomicAdd(&pool[8192 + (ct ? 64 : 0) + cg], crn);
      }
      ct = t; cg = g; acc = 0.f; crn = 0.f;
    }
    acc += fmaxf(xfin[(size_t)(c_XOFF[t] + n) * 64 + lane], 0.f);
    crn += 1.f;
  }
  if (ct >= 0) {
    atomicAdd(&pool[(ct ? 4096 : 0) + cg * 64 + lane], acc);
    if (lane == 0) atomicAdd(&pool[8192 + (ct ? 64 : 0) + cg], crn);
  }
}

__global__ void k_final(const float* pool, const float* lin_w, const float* lin_b, float* out) {
  int k = threadIdx.x;          // 128 = 64 graphs x 2 outputs
  int g = k >> 1, o = k & 1;
  float c0 = fmaxf(pool[8192 + g], 1.f);
  float c3 = fmaxf(pool[8256 + g], 1.f);
  float acc = lin_b[o];
  for (int i = 0; i < 64; ++i) {
    acc += (pool[g * 64 + i] / c0) * lin_w[o * 128 + i];
    acc += (pool[4096 + g * 64 + i] / c3) * lin_w[o * 128 + 64 + i];
  }
  out[g * 2 + o] = acc;
}

__global__ void k_bail(float* out) {
  if (threadIdx.x < 128) out[threadIdx.x] = 0.f;
}

// ---------------- host launch ----------------
extern "C" void kernel_launch(void* const* d_in, const int* in_sizes, int n_in,
                              void* d_out, int out_size, void* d_ws, size_t ws_size,
                              hipStream_t stream) {
  (void)in_sizes; (void)n_in; (void)out_size;
  // ---- workspace layout (float units) ----
  const size_t O_XA   = 0;            // 16,000,000
  const size_t O_XB   = 16000000;     // 16,000,000
  const size_t O_HS   = 32000000;     //  3,200,000 (bf16 hs: 100k rows x 64 x 2B)
  const size_t O_ALS  = 35200000;     //    660,000
  const size_t O_ALD  = 35860000;     //    660,000
  const size_t O_WV   = 36520000;     //      2,304
  const size_t O_BS   = 36522304;     //        512
  const size_t O_RP   = 36522816;     //    660,016 (int)
  const size_t O_BSC  = 37182832;     //      1,024 (int)
  const size_t O_ASX  = 37183856;     //  2,700,000 (int)
  const size_t O_CNT  = 39883856;     //    660,000 (int) — aliased as esc (300k) after CSR build
  const size_t O_FILL = 40543856;     //    660,000 (int)
  const size_t O_POOL = 41203856;     //      8,320
  const size_t NEED   = 41212176;     // floats (~165 MB)

  if (ws_size < NEED * 4) {           // graceful, deterministic bail (diagnostic)
    k_bail<<<1, 128, 0, stream>>>((float*)d_out);
    return;
  }

  const float* x0 = (const float*)d_in[0];
  const float* x1 = (const float*)d_in[1];
  const float* x2 = (const float*)d_in[2];
  const float* x3 = (const float*)d_in[3];
  const float* Wsrc = (const float*)d_in[4];
  const float* Wdst = (const float*)d_in[5];
  const float* asrc = (const float*)d_in[6];
  const float* adst = (const float*)d_in[7];
  const float* bias = (const float*)d_in[8];
  const float* lin_w = (const float*)d_in[9];
  const float* lin_b = (const float*)d_in[10];
  EdgePtrs Eg;
  for (int r = 0; r < 9; ++r) {
    Eg.s[r] = (const int*)d_in[11 + 2 * r];
    Eg.d[r] = (const int*)d_in[12 + 2 * r];
  }
  const int* bvar = (const int*)d_in[29];
  const int* bcon = (const int*)d_in[30];

  float* ws = (float*)d_ws;
  float* xA   = ws + O_XA;
  float* xB   = ws + O_XB;
  __hip_bfloat16* hs = (__hip_bfloat16*)(ws + O_HS);
  float* als  = ws + O_ALS;
  float* ald  = ws + O_ALD;
  float* wv   = ws + O_WV;
  float* bsum = ws + O_BS;
  int* rowptr = (int*)(ws + O_RP);
  int* bsc    = (int*)(ws + O_BSC);
  int* asx    = (int*)(ws + O_ASX);
  int* cnt    = (int*)(ws + O_CNT);
  int* fill   = (int*)(ws + O_FILL);
  float* esc  = ws + O_CNT;           // alias: cnt dead after CSR build
  float* pool = ws + O_POOL;

  const int h_NS[4]   = {100000, 20000, 50000, 80000};
  const int h_SRC[9]  = {0,0,0,2,3,1,2,3,3};
  const int h_DST[9]  = {1,2,3,3,3,0,0,0,2};
  const int h_XOFF[4] = {0,100000,120000,170000};
  const int h_ASOFF[9] = {0,100000,200000,300000,350000,430000,450000,500000,580000};
  const int h_ADOFF[9] = {0,20000,70000,150000,230000,310000,410000,510000,610000};

  // zero cnt + fill + pool (contiguous)
  hipMemsetAsync(cnt, 0, (size_t)(660000 + 660000 + 8320) * 4, stream);

  k_setup<<<37, 64, 0, stream>>>(Wsrc, Wdst, asrc, adst, bias, wv, bsum);

  // CSR build (layer-independent)
  k_count<<<(TOTEDGE + 255) / 256, 256, 0, stream>>>(Eg, cnt);
  int nb = (TOTSEG + 1023) / 1024;  // 645
  k_scan1<<<nb, 256, 0, stream>>>(cnt, bsc, TOTSEG);
  k_scan2<<<1, 1024, 0, stream>>>(bsc, nb, rowptr, TOTSEG, TOTEDGE);
  k_scan3<<<nb, 256, 0, stream>>>(cnt, bsc, rowptr, TOTSEG);
  k_fill<<<(TOTEDGE + 255) / 256, 256, 0, stream>>>(Eg, rowptr, fill, asx);

  for (int l = 0; l < 2; ++l) {
    const float* xin[4];
    if (l == 0) { xin[0] = x0; xin[1] = x1; xin[2] = x2; xin[3] = x3; }
    else {
      for (int t = 0; t < 4; ++t) xin[t] = xA + (size_t)h_XOFF[t] * 64;
    }
    float* xout = l ? xB : xA;
    int act = (l > 0);
    int relmask = l ? 0x0FC : 0x1FF;   // layer 2: dst types 1,2 unused -> skip r0,r1,r8

    AlphaP AP;
    AP.x0 = xin[0]; AP.x1 = xin[1]; AP.x2 = xin[2]; AP.x3 = xin[3];
    AP.als = als; AP.ald = ald;
    AP.wvs = wv + l * 576; AP.wvd = wv + 1152 + l * 576;
    AP.act = act; AP.smask = relmask; AP.dmask = relmask;
    k_alphas<<<(TOTROWS + 255) / 256, 256, 0, stream>>>(AP);

    int initw = l ? 180000 : TOTROWS;
    k_init<<<(initw + 3) / 4, 256, 0, stream>>>(xout, bsum + l * 256, l == 0);

    for (int r = 0; r < 9; ++r) {
      if (!((relmask >> r) & 1)) continue;
      int st = h_SRC[r], dt = h_DST[r];
      GemmP G;
      G.x = xin[st];
      G.W = Wsrc + ((size_t)l * 9 + r) * 4096;
      G.hs = hs;
      G.Ns = h_NS[st];
      G.act = act;
      int tiles = (G.Ns + 63) / 64;
      k_gemm<<<tiles, 256, 0, stream>>>(G);

      AggP A;
      A.hs = hs; A.als = als; A.ald = ald;
      A.rowptr = rowptr; A.asx = asx;
      A.xout = xout + (size_t)h_XOFF[dt] * 64;
      A.esc = esc;
      A.Nd = h_NS[dt]; A.asoff = h_ASOFF[r]; A.adoff = h_ADOFF[r];
      A.ebase = r * NEDGE;
      k_agg<<<(h_NS[dt] + 7) / 8, 256, 0, stream>>>(A);
    }
  }

  k_pool<<<512, 256, 0, stream>>>(xB, bvar, bcon, pool);
  k_final<<<1, 128, 0, stream>>>(pool, lin_w, lin_b, (float*)d_out);
}